// Round 15
// baseline (71.427 us; speedup 1.0000x reference)
//
#include <hip/hip_runtime.h>

#define NROWS 8192
#define DIM   256          // elements per row == bytes per row in fp8
#define BHALF 4096
#define NCHUNK 8           // col chunks per 128-row panel (1024 cols each)
#define SCALE 1.69864358f  // sqrt(2 * log2(e)): dot = sim * log2(e)
#define LN2F  0.69314718f

typedef unsigned char u8;
typedef __attribute__((ext_vector_type(16))) float f32x16;
typedef __attribute__((ext_vector_type(4))) int   i32x4;
typedef __attribute__((ext_vector_type(8))) int   i32x8;

__device__ inline void gload_lds16(const void* g, void* l) {
  __builtin_amdgcn_global_load_lds(
      (const __attribute__((address_space(1))) void*)g,
      (__attribute__((address_space(3))) void*)l, 16, 0, 0);
}

// exact OCP e4m3fn -> f32 (values here never reach NaN/448)
__device__ inline float fp8_to_f32(int b) {
  const int e = (b >> 3) & 15, m = b & 7;
  float mag = e ? __builtin_bit_cast(float, ((e + 120) << 23) | (m << 20))
                : (float)m * 0x1p-9f;
  return (b & 128) ? -mag : mag;
}

// Kernel 1: row-PAIR normalize (rows r and r+B together): quantize to fp8
// (scaled by sqrt(2*log2e) so Gram dot = sim*log2e), and precompute from the
// DEQUANTIZED values pos[r] (positive-pair dot, nats) and diag[r] (self-dot,
// log2 units). Zeroes rowsum / cnt / out (stream-ordered before sim).
__global__ __launch_bounds__(256) void nrm_kernel(const float* __restrict__ zi,
                                                  const float* __restrict__ zj,
                                                  u8* __restrict__ zn8,
                                                  float* __restrict__ rowsum,
                                                  float* __restrict__ pos,
                                                  float* __restrict__ diag,
                                                  int* __restrict__ cnt,
                                                  float* __restrict__ out) {
  const int t = threadIdx.x, b = blockIdx.x;
  const int gid = b * 256 + t;
  if (gid < NROWS) rowsum[gid] = 0.f;
  if (gid < 64) cnt[gid] = 0;
  if (gid == 0) out[0] = 0.f;

  const int w = t >> 6, l = t & 63;
#pragma unroll
  for (int q = 0; q < 2; ++q) {
    const int p = b * 8 + w * 2 + q;           // pair index 0..4095
    float4 vi = *(const float4*)(zi + (size_t)p * DIM + l * 4);
    float4 vj = *(const float4*)(zj + (size_t)p * DIM + l * 4);
    float ssi = vi.x * vi.x + vi.y * vi.y + vi.z * vi.z + vi.w * vi.w;
    float ssj = vj.x * vj.x + vj.y * vj.y + vj.z * vj.z + vj.w * vj.w;
#pragma unroll
    for (int m = 1; m < 64; m <<= 1) {
      ssi += __shfl_xor(ssi, m);
      ssj += __shfl_xor(ssj, m);
    }
    const float invi = SCALE / fmaxf(sqrtf(ssi), 1e-8f);
    const float invj = SCALE / fmaxf(sqrtf(ssj), 1e-8f);
    int pi = __builtin_amdgcn_cvt_pk_fp8_f32(vi.x * invi, vi.y * invi, 0, false);
    pi = __builtin_amdgcn_cvt_pk_fp8_f32(vi.z * invi, vi.w * invi, pi, true);
    int pj = __builtin_amdgcn_cvt_pk_fp8_f32(vj.x * invj, vj.y * invj, 0, false);
    pj = __builtin_amdgcn_cvt_pk_fp8_f32(vj.z * invj, vj.w * invj, pj, true);
    *(int*)(zn8 + (size_t)p * DIM + l * 4) = pi;
    *(int*)(zn8 + (size_t)(p + BHALF) * DIM + l * 4) = pj;

    // dequantized dot / self-dots (match MFMA values to summation rounding)
    float dot = 0.f, di = 0.f, dj = 0.f;
#pragma unroll
    for (int k2 = 0; k2 < 4; ++k2) {
      const float qi = fp8_to_f32((pi >> (8 * k2)) & 255);
      const float qj = fp8_to_f32((pj >> (8 * k2)) & 255);
      dot += qi * qj; di += qi * qi; dj += qj * qj;
    }
#pragma unroll
    for (int m = 1; m < 64; m <<= 1) {
      dot += __shfl_xor(dot, m);
      di  += __shfl_xor(di, m);
      dj  += __shfl_xor(dj, m);
    }
    if      (l == 0) pos[p] = dot * LN2F;            // nats
    else if (l == 1) pos[p + BHALF] = dot * LN2F;
    else if (l == 2) diag[p] = di;                   // log2 units
    else if (l == 3) diag[p + BHALF] = dj;
  }
}

// Kernel 2: BARRIER-FREE staged sweep. Wave w owns tile-strip w*32 (A) x the
// FULL 128-row panel (B in registers via direct-L2 prologue, pb[4][4]); each
// wave stages ONLY its own strip into a private 2x8KB LDS double-buffer with
// depth-2 prefetch. Steady state: counted vmcnt(8) on the wave's own FIFO
// staging loads, counted lgkmcnt on its own ds_reads, NO s_barrier, NO
// __syncthreads until the final plane reduce. Waves drift freely -> MFMA /
// exp2 / DS phases from 8 waves/CU interleave (the per-tile block lockstep
// was the measured ~2800cyc/tile residual; r13/r14 isolated it).
__global__ __launch_bounds__(256, 2) void sim_kernel(const u8* __restrict__ zn8,
                                                     float* __restrict__ rowsum,
                                                     const float* __restrict__ pos,
                                                     const float* __restrict__ diag,
                                                     int* __restrict__ cnt,
                                                     float* __restrict__ out) {
  __shared__ __align__(16) u8 Bsm[2][4][32 * DIM]; // 2 bufs x 4 waves x 8 KB
  __shared__ float plane[4][128];
  __shared__ float wsum[2];
  __shared__ int sfin;

  const int t = threadIdx.x;
  const int w = t >> 6, l = t & 63;
  const int n31 = l & 31, kh = l >> 5;  // operand row / k-half

  const int rp = (int)blockIdx.x >> 3;  // row panel 0..63
  const int ch = (int)blockIdx.x & 7;   // col chunk 0..7
  const int colbase = ch * 1024;        // zn8 row index of first streamed tile

  // per-wave staging of OWN 32-row strip: 8 gload_lds, chunk c = i*64 + l;
  // local row r = c>>4, dest linear c*16, source chunk inverse-swizzled
  // with salt r&7 (involution; matches RD32's read swizzle)
  auto STAGE = [&](int base_row, int d) {
    u8* dst = &Bsm[d][w][0];
#pragma unroll
    for (int i = 0; i < 8; ++i) {
      const int c = i * 64 + l;
      const int r = c >> 4, cd = c & 15;
      const int cs = (cd & 8) | ((cd ^ r) & 7);
      gload_lds16(zn8 + (size_t)(base_row + r) * DIM + cs * 16,
                  dst + i * 1024);     // wave-uniform base; lane adds l*16
    }
  };
  // swizzled fragment read from MY strip: 32B of local row `row`, k-step kk
  auto RD32 = [&](int d, int row, int kk) -> i32x8 {
    const int salt = row & 7;
    const u8* base = &Bsm[d][w][0] + row * DIM;
    const int c0 = kk * 4 + kh * 2;
    i32x4 lo = *(const i32x4*)(base + (((c0 & 8) | ((c0 ^ salt) & 7)) << 4));
    i32x4 hi = *(const i32x4*)(base + ((((c0 + 1) & 8) | (((c0 + 1) ^ salt) & 7)) << 4));
    return __builtin_shufflevector(lo, hi, 0, 1, 2, 3, 4, 5, 6, 7);
  };

  STAGE(colbase + w * 32, 0);           // tile0 strip -> buf0 (8 loads)
  STAGE(colbase + 128 + w * 32, 1);     // tile1 strip -> buf1 (8 loads)

  // panel fragments (B-operand) direct from L2 (r14-verified pattern):
  // row = rp*128 + pj*32 + n31, bytes kk*64 + kh*32 .. +32
  i32x8 pb[4][4];
#pragma unroll
  for (int pj = 0; pj < 4; ++pj)
#pragma unroll
    for (int kk = 0; kk < 4; ++kk) {
      const u8* base = zn8 + (size_t)(rp * 128 + pj * 32 + n31) * DIM
                       + kk * 64 + kh * 32;
      i32x4 lo = *(const i32x4*)(base);
      i32x4 hi = *(const i32x4*)(base + 16);
      pb[pj][kk] = __builtin_shufflevector(lo, hi, 0, 1, 2, 3, 4, 5, 6, 7);
    }

  float rsum[4] = {0.f, 0.f, 0.f, 0.f};
  f32x16 z16 = (f32x16)(0.f);

#pragma unroll 2
  for (int ti = 0; ti < 8; ++ti) {
    // my strip of tile ti landed: pb + stage(ti) done, stage(ti+1) may fly
    if (ti < 7) asm volatile("s_waitcnt vmcnt(8)" ::: "memory");
    else        asm volatile("s_waitcnt vmcnt(0)" ::: "memory");
    __builtin_amdgcn_sched_barrier(0);

    const int d = ti & 1;
    f32x16 acc[4];
    i32x8 af0 = RD32(d, n31, 0);
    i32x8 af1;
#pragma unroll
    for (int kk = 0; kk < 4; ++kk) {
      if (kk < 3) {
        i32x8 nxt = RD32(d, n31, kk + 1);
        if (kk & 1) af0 = nxt; else af1 = nxt;
        asm volatile("s_waitcnt lgkmcnt(2)" ::: "memory");
      } else {
        asm volatile("s_waitcnt lgkmcnt(0)" ::: "memory");
      }
      __builtin_amdgcn_sched_barrier(0);
      const i32x8 a = (kk & 1) ? af1 : af0;
      __builtin_amdgcn_s_setprio(1);
#pragma unroll
      for (int pj = 0; pj < 4; ++pj)
        acc[pj] = __builtin_amdgcn_mfma_scale_f32_32x32x64_f8f6f4(
            a, pb[pj][kk], (kk == 0) ? z16 : acc[pj],
            0, 0,                        // cbsz=fp8, blgp=fp8
            0, 0x7f7f7f7f,               // scale_a = 1.0 (e8m0 127)
            0, 0x7f7f7f7f);              // scale_b = 1.0
      __builtin_amdgcn_s_setprio(0);
    }

    // all my ds_reads of buf d retired (lgkmcnt(0) above) -> safe to restage
    if (ti < 6) STAGE(colbase + (ti + 2) * 128 + w * 32, d);  // depth-2

    // uniform epilogue: exp2 + lane-local row-sum (runs while loads fly)
#pragma unroll
    for (int pj = 0; pj < 4; ++pj) {
      float e0 = 0.f, e1 = 0.f, e2 = 0.f, e3 = 0.f;
#pragma unroll
      for (int r16 = 0; r16 < 16; r16 += 4) {
        e0 += __builtin_amdgcn_exp2f(acc[pj][r16]);
        e1 += __builtin_amdgcn_exp2f(acc[pj][r16 + 1]);
        e2 += __builtin_amdgcn_exp2f(acc[pj][r16 + 2]);
        e3 += __builtin_amdgcn_exp2f(acc[pj][r16 + 3]);
      }
      rsum[pj] += (e0 + e1) + (e2 + e3);
    }
  }

  // panel row pj*32+n lives in lanes n,n+32: one xor, then 4-wave plane sum
#pragma unroll
  for (int pj = 0; pj < 4; ++pj) {
    rsum[pj] += __shfl_xor(rsum[pj], 32);
    if (l < 32) plane[w][pj * 32 + l] = rsum[pj];
  }
  __syncthreads();                      // the ONLY block-wide sync

  // ---- fence-free fused finish ----
  if (t < 128)
    atomicAdd(&rowsum[rp * 128 + t],
              (plane[0][t] + plane[1][t]) + (plane[2][t] + plane[3][t]));
  asm volatile("s_waitcnt vmcnt(0)" ::: "memory");   // my atomics at coherence
  __syncthreads();
  if (t == 0) sfin = (atomicAdd(&cnt[rp], 1) == NCHUNK - 1);
  __syncthreads();
  if (sfin) {                           // 8th arrival: all panels' adds landed
    float v = 0.f;
    if (t < 128) {
      const int r = rp * 128 + t;
      float s = atomicAdd(&rowsum[r], 0.f);          // coherent read
      v = logf(s - __builtin_amdgcn_exp2f(diag[r])) - pos[r];
    }
#pragma unroll
    for (int m = 1; m < 64; m <<= 1) v += __shfl_xor(v, m);
    if (l == 0 && t < 128) wsum[w] = v;
    __syncthreads();
    if (t == 0) atomicAdd(out, (wsum[0] + wsum[1]) * (1.f / NROWS));
  }
}

extern "C" void kernel_launch(void* const* d_in, const int* in_sizes, int n_in,
                              void* d_out, int out_size, void* d_ws, size_t ws_size,
                              hipStream_t stream) {
  const float* zi = (const float*)d_in[0];
  const float* zj = (const float*)d_in[1];

  u8*    zn8    = (u8*)d_ws;                                        // 2 MB
  float* rowsum = (float*)((char*)d_ws + (size_t)NROWS * DIM);      // 32 KB
  float* pos    = (float*)((char*)rowsum + (size_t)NROWS * 4);      // 32 KB
  float* diag   = (float*)((char*)pos + (size_t)NROWS * 4);         // 32 KB
  int*   cnt    = (int*)((char*)diag + (size_t)NROWS * 4);          // 256 B
  float* out    = (float*)d_out;

  nrm_kernel<<<512, 256, 0, stream>>>(zi, zj, zn8, rowsum, pos, diag, cnt, out);
  sim_kernel<<<64 * NCHUNK, 256, 0, stream>>>(zn8, rowsum, pos, diag, cnt, out);
}

// Round 16
// 31.662 us; speedup vs baseline: 2.2559x; 2.2559x over previous
//
#include <hip/hip_runtime.h>

#define NROWS 8192
#define DIM   256          // elements per row == bytes per row in fp8
#define BHALF 4096
#define NCHUNK 8           // col chunks per 128-row panel (1024 cols each)
#define SCALE 1.69864358f  // sqrt(2 * log2(e)): dot = sim * log2(e)
#define LN2F  0.69314718f

typedef unsigned char u8;
typedef __attribute__((ext_vector_type(16))) float f32x16;
typedef __attribute__((ext_vector_type(4))) int   i32x4;
typedef __attribute__((ext_vector_type(8))) int   i32x8;

__device__ inline void gload_lds16(const void* g, void* l) {
  __builtin_amdgcn_global_load_lds(
      (const __attribute__((address_space(1))) void*)g,
      (__attribute__((address_space(3))) void*)l, 16, 0, 0);
}

// exact OCP e4m3fn -> f32 (values here never reach NaN/448)
__device__ inline float fp8_to_f32(int b) {
  const int e = (b >> 3) & 15, m = b & 7;
  float mag = e ? __builtin_bit_cast(float, ((e + 120) << 23) | (m << 20))
                : (float)m * 0x1p-9f;
  return (b & 128) ? -mag : mag;
}

// Kernel 1: row-PAIR normalize (rows r and r+B together): quantize to fp8
// (scaled by sqrt(2*log2e) so Gram dot = sim*log2e), and precompute from the
// DEQUANTIZED values pos[r] (positive-pair dot, nats) and diag[r] (self-dot,
// log2 units). Zeroes rowsum / cnt / out (stream-ordered before sim).
__global__ __launch_bounds__(256) void nrm_kernel(const float* __restrict__ zi,
                                                  const float* __restrict__ zj,
                                                  u8* __restrict__ zn8,
                                                  float* __restrict__ rowsum,
                                                  float* __restrict__ pos,
                                                  float* __restrict__ diag,
                                                  int* __restrict__ cnt,
                                                  float* __restrict__ out) {
  const int t = threadIdx.x, b = blockIdx.x;
  const int gid = b * 256 + t;
  if (gid < NROWS) rowsum[gid] = 0.f;
  if (gid < 64) cnt[gid] = 0;
  if (gid == 0) out[0] = 0.f;

  const int w = t >> 6, l = t & 63;
#pragma unroll
  for (int q = 0; q < 2; ++q) {
    const int p = b * 8 + w * 2 + q;           // pair index 0..4095
    float4 vi = *(const float4*)(zi + (size_t)p * DIM + l * 4);
    float4 vj = *(const float4*)(zj + (size_t)p * DIM + l * 4);
    float ssi = vi.x * vi.x + vi.y * vi.y + vi.z * vi.z + vi.w * vi.w;
    float ssj = vj.x * vj.x + vj.y * vj.y + vj.z * vj.z + vj.w * vj.w;
#pragma unroll
    for (int m = 1; m < 64; m <<= 1) {
      ssi += __shfl_xor(ssi, m);
      ssj += __shfl_xor(ssj, m);
    }
    const float invi = SCALE / fmaxf(sqrtf(ssi), 1e-8f);
    const float invj = SCALE / fmaxf(sqrtf(ssj), 1e-8f);
    int pi = __builtin_amdgcn_cvt_pk_fp8_f32(vi.x * invi, vi.y * invi, 0, false);
    pi = __builtin_amdgcn_cvt_pk_fp8_f32(vi.z * invi, vi.w * invi, pi, true);
    int pj = __builtin_amdgcn_cvt_pk_fp8_f32(vj.x * invj, vj.y * invj, 0, false);
    pj = __builtin_amdgcn_cvt_pk_fp8_f32(vj.z * invj, vj.w * invj, pj, true);
    *(int*)(zn8 + (size_t)p * DIM + l * 4) = pi;
    *(int*)(zn8 + (size_t)(p + BHALF) * DIM + l * 4) = pj;

    // dequantized dot / self-dots (match MFMA values to summation rounding)
    float dot = 0.f, di = 0.f, dj = 0.f;
#pragma unroll
    for (int k2 = 0; k2 < 4; ++k2) {
      const float qi = fp8_to_f32((pi >> (8 * k2)) & 255);
      const float qj = fp8_to_f32((pj >> (8 * k2)) & 255);
      dot += qi * qj; di += qi * qi; dj += qj * qj;
    }
#pragma unroll
    for (int m = 1; m < 64; m <<= 1) {
      dot += __shfl_xor(dot, m);
      di  += __shfl_xor(di, m);
      dj  += __shfl_xor(dj, m);
    }
    if      (l == 0) pos[p] = dot * LN2F;            // nats
    else if (l == 1) pos[p + BHALF] = dot * LN2F;
    else if (l == 2) diag[p] = di;                   // log2 units
    else if (l == 3) diag[p + BHALF] = dj;
  }
}

// Kernel 2: r12 structure (best measured: 31.7us) + ONE change: odd blocks
// walk the 8 tiles in rotated order (ti = lt+4 mod 8). Uniform epilogue makes
// order arbitrary; co-resident block pairs then never compute the same tile
// -> their MFMA / exp2 bursts lose their common alignment anchor (r9 PMC:
// the two phases are additive; the only untested mechanism for that is
// inter-block phase-locking).
__global__ __launch_bounds__(256, 2) void sim_kernel(const u8* __restrict__ zn8,
                                                     float* __restrict__ rowsum,
                                                     const float* __restrict__ pos,
                                                     const float* __restrict__ diag,
                                                     int* __restrict__ cnt,
                                                     float* __restrict__ out) {
  __shared__ __align__(16) u8 Bsm[2][128 * DIM];   // 2 x 32 KB
  __shared__ float plane[4][128];
  __shared__ float wsum[2];
  __shared__ int sfin;

  const int t = threadIdx.x;
  const int w = t >> 6, l = t & 63;     // w = tile-row strip (32 rows)
  const int n31 = l & 31, kh = l >> 5;  // operand row / k-half

  const int rp = (int)blockIdx.x >> 3;  // row panel 0..63
  const int ch = (int)blockIdx.x & 7;   // col chunk 0..7
  const int colbase = ch * 1024;        // zn8 row index of first streamed tile
  const int rot = ((int)blockIdx.x & 1) << 2;      // de-phase co-resident pair

  // precomputed staging offsets (ti-invariant): source inverse-swizzled (r&7)
  int soff[8], doff[8];
#pragma unroll
  for (int i = 0; i < 8; ++i) {
    int c = i * 256 + t;                // 0..2047 16B-chunks
    int r = c >> 4, cd = c & 15;
    int cs = (cd & 8) | ((cd ^ r) & 7);
    soff[i] = r * DIM + cs * 16;
    doff[i] = (i * 256 + w * 64) * 16;
  }
  auto STAGE = [&](int base_row, u8* dst) {
#pragma unroll
    for (int i = 0; i < 8; ++i)
      gload_lds16(zn8 + (size_t)base_row * DIM + soff[i], dst + doff[i]);
  };
  // swizzled fragment read for 32x32x64: 32B of row `row`, k-step kk (0..3).
  // logical chunks c0,c0+1 with c0 = kk*4 + kh*2; phys = (c&8)|((c^salt)&7).
  // (verified end-to-end in r8/r12: absmax 0)
  auto RD32 = [&](const u8* buf, int row, int kk) -> i32x8 {
    const int salt = row & 7;
    const u8* base = buf + row * DIM;
    const int c0 = kk * 4 + kh * 2;
    i32x4 lo = *(const i32x4*)(base + (((c0 & 8) | ((c0 ^ salt) & 7)) << 4));
    i32x4 hi = *(const i32x4*)(base + ((((c0 + 1) & 8) | (((c0 + 1) ^ salt) & 7)) << 4));
    return __builtin_shufflevector(lo, hi, 0, 1, 2, 3, 4, 5, 6, 7);
  };

  STAGE(rp * 128, &Bsm[0][0]);          // panel -> buf0 (8 loads)
  STAGE(colbase + rot * 128, &Bsm[1][0]);   // first tile -> buf1 (16 in flight)
  asm volatile("s_waitcnt vmcnt(8)" ::: "memory");   // panel landed
  __builtin_amdgcn_sched_barrier(0);
  __builtin_amdgcn_s_barrier();
  __builtin_amdgcn_sched_barrier(0);

  i32x8 pb[4][4];                       // panel B-frags [pj][kk], 128 VGPR
#pragma unroll
  for (int pj = 0; pj < 4; ++pj)
#pragma unroll
    for (int kk = 0; kk < 4; ++kk)
      pb[pj][kk] = RD32(&Bsm[0][0], pj * 32 + n31, kk);
  asm volatile("s_waitcnt lgkmcnt(0)" ::: "memory");
  __builtin_amdgcn_sched_barrier(0);
  // no barrier: first tile's barrier below also proves all waves finished pb

  float rsum[4] = {0.f, 0.f, 0.f, 0.f};

#pragma unroll 2
  for (int lt = 0; lt < 8; ++lt) {
    asm volatile("s_waitcnt vmcnt(0)" ::: "memory");  // tile lt landed (mine)
    __builtin_amdgcn_sched_barrier(0);
    __builtin_amdgcn_s_barrier();       // all waves: lt ready AND lt-1 readers done
    __builtin_amdgcn_sched_barrier(0);

    const u8* Bb = &Bsm[(lt + 1) & 1][0];            // tile lt's buffer
    if (lt < 7) {
      const int tnext = ((lt + 1) + rot) & 7;        // rotated tile order
      STAGE(colbase + tnext * 128, &Bsm[lt & 1][0]); // depth-1
    }

    f32x16 acc[4];
#pragma unroll
    for (int pj = 0; pj < 4; ++pj) acc[pj] = (f32x16)(0.f);

    i32x8 af0 = RD32(Bb, w * 32 + n31, 0);
    i32x8 af1;
#pragma unroll
    for (int kk = 0; kk < 4; ++kk) {
      if (kk < 3) {
        i32x8 nxt = RD32(Bb, w * 32 + n31, kk + 1);
        if (kk & 1) af0 = nxt; else af1 = nxt;
        asm volatile("s_waitcnt lgkmcnt(2)" ::: "memory");
      } else {
        asm volatile("s_waitcnt lgkmcnt(0)" ::: "memory");
      }
      __builtin_amdgcn_sched_barrier(0);
      const i32x8 a = (kk & 1) ? af1 : af0;
      __builtin_amdgcn_s_setprio(1);
#pragma unroll
      for (int pj = 0; pj < 4; ++pj)
        acc[pj] = __builtin_amdgcn_mfma_scale_f32_32x32x64_f8f6f4(
            a, pb[pj][kk], acc[pj],
            0, 0,                        // cbsz=fp8, blgp=fp8
            0, 0x7f7f7f7f,               // scale_a = 1.0 (e8m0 127)
            0, 0x7f7f7f7f);              // scale_b = 1.0
      __builtin_amdgcn_s_setprio(0);
    }

    // uniform epilogue: exp2 + lane-local row-sum (no special cases)
#pragma unroll
    for (int pj = 0; pj < 4; ++pj) {
      float e0 = 0.f, e1 = 0.f, e2 = 0.f, e3 = 0.f;
#pragma unroll
      for (int r16 = 0; r16 < 16; r16 += 4) {
        e0 += __builtin_amdgcn_exp2f(acc[pj][r16]);
        e1 += __builtin_amdgcn_exp2f(acc[pj][r16 + 1]);
        e2 += __builtin_amdgcn_exp2f(acc[pj][r16 + 2]);
        e3 += __builtin_amdgcn_exp2f(acc[pj][r16 + 3]);
      }
      rsum[pj] += (e0 + e1) + (e2 + e3);
    }
  }

  // panel row pj*32+n lives in lanes n and n+32: one xor, then 4-plane sum
#pragma unroll
  for (int pj = 0; pj < 4; ++pj) {
    rsum[pj] += __shfl_xor(rsum[pj], 32);
    if (l < 32) plane[w][pj * 32 + l] = rsum[pj];
  }
  __syncthreads();

  // ---- fence-free fused finish ----
  if (t < 128)
    atomicAdd(&rowsum[rp * 128 + t],
              (plane[0][t] + plane[1][t]) + (plane[2][t] + plane[3][t]));
  asm volatile("s_waitcnt vmcnt(0)" ::: "memory");   // my atomics at coherence
  __syncthreads();
  if (t == 0) sfin = (atomicAdd(&cnt[rp], 1) == NCHUNK - 1);
  __syncthreads();
  if (sfin) {                           // 8th arrival: all panels' adds landed
    float v = 0.f;
    if (t < 128) {
      const int r = rp * 128 + t;
      float s = atomicAdd(&rowsum[r], 0.f);          // coherent read
      v = logf(s - __builtin_amdgcn_exp2f(diag[r])) - pos[r];
    }
#pragma unroll
    for (int m = 1; m < 64; m <<= 1) v += __shfl_xor(v, m);
    if (l == 0 && t < 128) wsum[w] = v;
    __syncthreads();
    if (t == 0) atomicAdd(out, (wsum[0] + wsum[1]) * (1.f / NROWS));
  }
}

extern "C" void kernel_launch(void* const* d_in, const int* in_sizes, int n_in,
                              void* d_out, int out_size, void* d_ws, size_t ws_size,
                              hipStream_t stream) {
  const float* zi = (const float*)d_in[0];
  const float* zj = (const float*)d_in[1];

  u8*    zn8    = (u8*)d_ws;                                        // 2 MB
  float* rowsum = (float*)((char*)d_ws + (size_t)NROWS * DIM);      // 32 KB
  float* pos    = (float*)((char*)rowsum + (size_t)NROWS * 4);      // 32 KB
  float* diag   = (float*)((char*)pos + (size_t)NROWS * 4);         // 32 KB
  int*   cnt    = (int*)((char*)diag + (size_t)NROWS * 4);          // 256 B
  float* out    = (float*)d_out;

  nrm_kernel<<<512, 256, 0, stream>>>(zi, zj, zn8, rowsum, pos, diag, cnt, out);
  sim_kernel<<<64 * NCHUNK, 256, 0, stream>>>(zn8, rowsum, pos, diag, cnt, out);
}